// Round 1
// baseline (107.268 us; speedup 1.0000x reference)
//
#include <hip/hip_runtime.h>

constexpr int L = 12;
constexpr int B = 4, T = 2048, H = 16, D = 64;
constexpr int NPOS = B * T * H;                     // 131072 positions (b,t,h)
constexpr long long SLAYER = (long long)NPOS * D;   // elements per layer slice

// M[d][d2] = sum_e Wq[e][d] * Wk[e][d2]   (so score_l = x^T M y_l)
__global__ __launch_bounds__(64) void cla_precompute_M(
    const float* __restrict__ Wq, const float* __restrict__ Wk,
    float* __restrict__ M) {
  const int d  = blockIdx.x;    // 64 blocks
  const int d2 = threadIdx.x;   // 64 threads
  float acc = 0.f;
  #pragma unroll
  for (int e = 0; e < D; ++e)
    acc = fmaf(Wq[e * D + d], Wk[e * D + d2], acc);
  M[d * D + d2] = acc;
}

// 16 lanes per position; each lane owns d-chunk [4j, 4j+4).
// Single pass over all_layers: y[l] chunks held in registers for both the
// score dot-products and the final weighted sum.
__global__ __launch_bounds__(256) void cla_main(
    const float* __restrict__ cur, const float* __restrict__ all,
    const float* __restrict__ M, const float* __restrict__ scales,
    const float* __restrict__ temperature, float* __restrict__ out) {
  __shared__ float Mlds[D * D];
  {
    const float4* src = (const float4*)M;
    float4* dst = (float4*)Mlds;
    #pragma unroll
    for (int i = 0; i < 4; ++i)
      dst[threadIdx.x + 256 * i] = src[threadIdx.x + 256 * i];
  }
  __syncthreads();

  const int gt = blockIdx.x * 256 + threadIdx.x;
  const int p  = gt >> 4;   // position index
  const int j  = gt & 15;   // chunk lane within position

  const float inv_scale = 1.0f / (8.0f * fabsf(temperature[0]));  // sqrt(64)=8

  // scales into registers (uniform, L1/scalar cached)
  float scl[L];
  #pragma unroll
  for (int l = 0; l < L; ++l) scl[l] = scales[l];

  const size_t base = (size_t)p * D + (size_t)j * 4;
  const float4 xv = *(const float4*)(cur + base);

  float4 y[L];
  #pragma unroll
  for (int l = 0; l < L; ++l)
    y[l] = *(const float4*)(all + (size_t)l * SLAYER + base);

  // v[c] = sum_d M[d][4j+c] * x[d]; x[d] lives on lane (d>>2), comp (d&3)
  float v0 = 0.f, v1 = 0.f, v2 = 0.f, v3 = 0.f;
  const float xc[4] = {xv.x, xv.y, xv.z, xv.w};
  #pragma unroll
  for (int d = 0; d < D; ++d) {
    const float xd = __shfl(xc[d & 3], d >> 2, 16);
    const float4 m = *(const float4*)(Mlds + d * D + j * 4);
    v0 = fmaf(xd, m.x, v0);
    v1 = fmaf(xd, m.y, v1);
    v2 = fmaf(xd, m.z, v2);
    v3 = fmaf(xd, m.w, v3);
  }

  // scores: per-lane partial dot, reduce across the 16-lane group
  float sc[L];
  #pragma unroll
  for (int l = 0; l < L; ++l) {
    float s = v0 * y[l].x + v1 * y[l].y + v2 * y[l].z + v3 * y[l].w;
    s += __shfl_xor(s, 1, 16);
    s += __shfl_xor(s, 2, 16);
    s += __shfl_xor(s, 4, 16);
    s += __shfl_xor(s, 8, 16);
    sc[l] = s * inv_scale;
  }

  // softmax over L (redundant per lane)
  float mx = sc[0];
  #pragma unroll
  for (int l = 1; l < L; ++l) mx = fmaxf(mx, sc[l]);
  float sum = 0.f;
  #pragma unroll
  for (int l = 0; l < L; ++l) { sc[l] = __expf(sc[l] - mx); sum += sc[l]; }
  const float inv_sum = 1.0f / sum;

  // attn = softmax * scales; renormalize; final weight multiplies scales again
  float w[L];
  float ssum = 0.f;
  #pragma unroll
  for (int l = 0; l < L; ++l) { w[l] = sc[l] * inv_sum * scl[l]; ssum += w[l]; }
  const float r = 1.0f / (ssum + 1e-6f);

  float o0 = 0.f, o1 = 0.f, o2 = 0.f, o3 = 0.f;
  #pragma unroll
  for (int l = 0; l < L; ++l) {
    const float wl = w[l] * r * scl[l];
    o0 = fmaf(wl, y[l].x, o0);
    o1 = fmaf(wl, y[l].y, o1);
    o2 = fmaf(wl, y[l].z, o2);
    o3 = fmaf(wl, y[l].w, o3);
  }
  *(float4*)(out + base) = make_float4(o0, o1, o2, o3);
}

extern "C" void kernel_launch(void* const* d_in, const int* in_sizes, int n_in,
                              void* d_out, int out_size, void* d_ws, size_t ws_size,
                              hipStream_t stream) {
  const float* cur    = (const float*)d_in[0];
  const float* all    = (const float*)d_in[1];
  const float* Wq     = (const float*)d_in[2];
  const float* Wk     = (const float*)d_in[3];
  const float* scales = (const float*)d_in[4];
  const float* temp   = (const float*)d_in[5];
  float* M = (float*)d_ws;   // 16 KB scratch for Wq^T Wk

  cla_precompute_M<<<64, 64, 0, stream>>>(Wq, Wk, M);

  const int total_threads = NPOS * 16;  // 16 lanes per position
  cla_main<<<total_threads / 256, 256, 0, stream>>>(cur, all, M, scales, temp,
                                                    (float*)d_out);
}